// Round 9
// baseline (1524.669 us; speedup 1.0000x reference)
//
#include <hip/hip_runtime.h>
#include <stdint.h>

#define NB   8
#define NPTS 4096
#define CINV 64
#define MC   1024
#define KNB  64
#define NE   (NB*MC*KNB)
#define K1   67
#define CH1  64
#define CH2  64
#define CH3  128
#define NSLOT 64
#define CAP  2048
#define NTASK (NB*MC)
#define NBLK 256      // == #CUs; LDS padded >80KB -> exactly 1 block/CU -> FPS blocks isolated

typedef unsigned short u16;
typedef unsigned int   u32;
typedef unsigned long long u64;

static __device__ __forceinline__ float bf2f(u16 b){ return __uint_as_float(((u32)b)<<16); }
static __device__ __forceinline__ u16  f2bf(float f){
  u32 u = __float_as_uint(f);
  return (u16)((u + 0x7fffu + ((u>>16)&1u)) >> 16);
}
// Exact replica of reference distance: square each diff, sum as (x+y)+z, NO fma contraction.
static __device__ __forceinline__ float d2ref(float ax,float ay,float az,
                                              float bx,float by,float bz){
  float dx = ax-bx, dy = ay-by, dz = az-bz;
  return __fadd_rn(__fadd_rn(__fmul_rn(dx,dx), __fmul_rn(dy,dy)), __fmul_rn(dz,dz));
}
static __device__ __forceinline__ float wsum(float v){
  #pragma unroll
  for (int off = 32; off > 0; off >>= 1) v += __shfl_xor(v, off);
  return v;
}
static __device__ __forceinline__ float wmax(float v){
  #pragma unroll
  for (int off = 32; off > 0; off >>= 1) v = fmaxf(v, __shfl_xor(v, off));
  return v;
}
// One DPP max step: v = max(v, dpp_shuffle(v)). Pure VALU (no DS pipe).
template<int CTRL, int RMASK>
static __device__ __forceinline__ float dppmaxstep(float v){
  int t = __builtin_amdgcn_update_dpp(__float_as_int(v), __float_as_int(v),
                                      CTRL, RMASK, 0xF, false);
  return fmaxf(v, __int_as_float(t));
}
// Full wave64 max -> broadcast via readlane(63).
static __device__ __forceinline__ float wavemax_dpp(float v){
  v = dppmaxstep<0xB1, 0xF>(v);
  v = dppmaxstep<0x4E, 0xF>(v);
  v = dppmaxstep<0x141,0xF>(v);
  v = dppmaxstep<0x140,0xF>(v);
  v = dppmaxstep<0x142,0xA>(v);
  v = dppmaxstep<0x143,0xC>(v);
  return __int_as_float(__builtin_amdgcn_readlane(__float_as_int(v), 63));
}

// ---------------------------------------------------------------- fused front kernel
struct FpsL {
  float px[NPTS], py[NPTS], pz[NPTS];
  int   sIdx[MC];
  float4 cand[8];    // (d,x,y,z), double-buffered 2x4
  int    cIv[8];
  float4 cbuf[16];   // centroid staging: flush 16 rows/iteration-tile to global
};
struct WkL {
  u64   keys[CAP];        // ball-query sort keys
  float Hs[64*69];        // stage-1 H tile (odd pitch)
  int   nbrS[64];
  float red[4][32];
  float cxyz[3];
  int   scnt;
  int   task;
};
union FrontL { FpsL f; WkL w; };

__global__ __launch_bounds__(256) void k_front(const float* __restrict__ x,
                                               const float* __restrict__ pos,
                                               float* __restrict__ centf,
                                               float* __restrict__ out_cent,
                                               float* __restrict__ out_bsel,
                                               const float* __restrict__ W1,
                                               float* __restrict__ Spart,
                                               u16* __restrict__ y1g,
                                               int* __restrict__ cntpc,
                                               int* __restrict__ cnt_total,
                                               int* __restrict__ progress,
                                               int* __restrict__ taskctr) {
  __shared__ FrontL L;
  __shared__ char lds_pad[28672];   // push LDS >80KB -> exactly 1 block/CU (FPS isolation)
  (void)lds_pad;
  const int tid = threadIdx.x;

  if (blockIdx.x < NB) {
    // =========================== FPS producer: 4 waves, 1 barrier/iter, batched publishing
    const int b = blockIdx.x;
    for (int i = tid; i < NPTS; i += 256) {
      size_t o = ((size_t)b*NPTS + i)*3;
      L.f.px[i] = pos[o]; L.f.py[i] = pos[o+1]; L.f.pz[i] = pos[o+2];
    }
    __syncthreads();

    float cxr[16], cyr[16], czr[16], dist[16];
    #pragma unroll
    for (int j = 0; j < 16; ++j) {
      int p = tid*16 + j;
      cxr[j] = L.f.px[p]; cyr[j] = L.f.py[p]; czr[j] = L.f.pz[p];
      dist[j] = 1e10f;
    }
    const int lane = tid & 63, w = tid >> 6;
    float qx = L.f.px[0], qy = L.f.py[0], qz = L.f.pz[0];
    if (tid == 0) {
      L.f.sIdx[0] = 0;
      L.f.cbuf[0] = make_float4(qx, qy, qz, 0.f);
    }

    for (int it = 1; it < MC; ++it) {
      float bv = -1.f, bx = 0.f, by = 0.f, bz = 0.f; int bi = 0;
      #pragma unroll
      for (int j = 0; j < 16; ++j) {
        float d  = d2ref(cxr[j], cyr[j], czr[j], qx, qy, qz);
        float nd = fminf(dist[j], d);
        dist[j] = nd;
        if (nd > bv) { bv = nd; bi = tid*16 + j; bx = cxr[j]; by = cyr[j]; bz = czr[j]; }
      }
      // in-wave max (DPP, VALU-only); lowest winning lane = lowest index
      float gmax = wavemax_dpp(bv);
      u64 mm = __ballot(bv == gmax);
      int wl = __ffsll((unsigned long long)mm) - 1;
      const int base = (it & 1) * 4;
      if (lane == wl) {
        L.f.cand[base + w] = make_float4(gmax, bx, by, bz);
        L.f.cIv[base + w]  = bi;
      }
      __syncthreads();
      // every wave resolves the 4 candidates redundantly; winner coords via quad shfl
      float4 cq = L.f.cand[base + (lane & 3)];
      float dm = cq.x;
      dm = dppmaxstep<0xB1, 0xF>(dm);    // quad_perm [1,0,3,2]
      dm = dppmaxstep<0x4E, 0xF>(dm);    // quad_perm [2,3,0,1] -> quad-max everywhere
      u64 m2 = __ballot(cq.x == dm);
      int wc = (__ffsll((unsigned long long)m2) - 1) & 3;  // lowest cand = lowest wave = lowest idx
      int src = (lane & ~3) | wc;
      qx = __shfl(cq.y, src); qy = __shfl(cq.z, src); qz = __shfl(cq.w, src);
      // flush PREVIOUS 16-row tile (rows it-16..it-1, slots 0..15) before overwriting slot it&15
      if ((it & 15) == 0 && tid < 16) {
        int mrow = it - 16 + tid;
        float4 cc = L.f.cbuf[tid];
        int r = b*MC + mrow;
        centf[r*3+0] = cc.x; centf[r*3+1] = cc.y; centf[r*3+2] = cc.z;
        __threadfence();
        if (tid == 0)
          __hip_atomic_store(progress + b, it, __ATOMIC_RELAXED, __HIP_MEMORY_SCOPE_AGENT);
      }
      if (tid == 0) {
        L.f.sIdx[it] = L.f.cIv[base + wc];
        L.f.cbuf[it & 15] = make_float4(qx, qy, qz, 0.f);
      }
    }
    __syncthreads();
    // final tile flush (rows MC-16..MC-1) + progress = MC
    if (tid < 16) {
      int mrow = MC - 16 + tid;
      float4 cc = L.f.cbuf[tid];
      int r = b*MC + mrow;
      centf[r*3+0] = cc.x; centf[r*3+1] = cc.y; centf[r*3+2] = cc.z;
      __threadfence();
      if (tid == 0)
        __hip_atomic_store(progress + b, MC, __ATOMIC_RELAXED, __HIP_MEMORY_SCOPE_AGENT);
    }
    // epilogue: out_cent / out_bsel from sIdx (off the critical path)
    for (int m2_ = tid; m2_ < MC; m2_ += 256) {
      int i = L.f.sIdx[m2_];
      int r = b*MC + m2_;
      out_cent[r*3+0] = L.f.px[i]; out_cent[r*3+1] = L.f.py[i]; out_cent[r*3+2] = L.f.pz[i];
      out_bsel[r] = (float)b;
    }
    return;
  }

  // =========================== persistent workers: ball query + stage-1 per centroid
  for (;;) {
    if (tid == 0) {
      int t = atomicAdd(taskctr, 1);
      L.w.task = t;
      if (t < NTASK) {
        int m = t >> 3, b = t & 7;
        while (__hip_atomic_load(progress + b, __ATOMIC_ACQUIRE, __HIP_MEMORY_SCOPE_AGENT) < m + 1)
          __builtin_amdgcn_s_sleep(8);
        int bm = b*MC + m;
        L.w.cxyz[0] = __hip_atomic_load(centf + bm*3 + 0, __ATOMIC_RELAXED, __HIP_MEMORY_SCOPE_AGENT);
        L.w.cxyz[1] = __hip_atomic_load(centf + bm*3 + 1, __ATOMIC_RELAXED, __HIP_MEMORY_SCOPE_AGENT);
        L.w.cxyz[2] = __hip_atomic_load(centf + bm*3 + 2, __ATOMIC_RELAXED, __HIP_MEMORY_SCOPE_AGENT);
      }
      L.w.scnt = 0;
    }
    __syncthreads();
    const int t = L.w.task;
    if (t >= NTASK) return;
    const int m = t >> 3, b = t & 7, bm = b*MC + m;
    const float cx = L.w.cxyz[0], cy = L.w.cxyz[1], cz = L.w.cxyz[2];

    // ---- ball query (exact ref semantics)
    for (int i = tid; i < NPTS; i += 256) {
      size_t o = ((size_t)b*NPTS + i)*3;
      float d = d2ref(cx, cy, cz, pos[o], pos[o+1], pos[o+2]);
      if (d <= 0.04f) {
        int p = atomicAdd(&L.w.scnt, 1);
        if (p < CAP) L.w.keys[p] = ((u64)__float_as_uint(d) << 32) | (u32)i;
      }
    }
    __syncthreads();
    int n = L.w.scnt; if (n > CAP) n = CAP;
    int P = 64; while (P < n) P <<= 1;
    for (int i = n + tid; i < P; i += 256) L.w.keys[i] = ~0ull;
    __syncthreads();
    for (int ks = 2; ks <= P; ks <<= 1)
      for (int js = ks >> 1; js > 0; js >>= 1) {
        for (int i = tid; i < P; i += 256) {
          int l = i ^ js;
          if (l > i) {
            u64 a = L.w.keys[i], c = L.w.keys[l];
            bool up = ((i & ks) == 0);
            if ((a > c) == up) { L.w.keys[i] = c; L.w.keys[l] = a; }
          }
        }
        __syncthreads();
      }
    const int c = n < KNB ? n : KNB;
    if (tid < KNB) L.w.nbrS[tid] = (tid < c) ? (int)(u32)(L.w.keys[tid] & 0xffffffffu) : 0;
    if (tid == 0) { cntpc[bm] = c; atomicAdd(cnt_total, c); }
    __syncthreads();

    // ---- stage-1: H = [x_j, p_j - c_i] (64x67) staged in LDS
    {
      const int ge = tid >> 2, qb = tid & 3;
      const float4* xr = (const float4*)(x + ((size_t)(b*NPTS + L.w.nbrS[ge]))*CINV);
      #pragma unroll
      for (int rep = 0; rep < 4; ++rep) {
        int q = qb + rep*4;
        float4 v = xr[q];
        float* d = L.w.Hs + ge*69 + q*4;
        d[0] = v.x; d[1] = v.y; d[2] = v.z; d[3] = v.w;
      }
    }
    if (tid < 64) {
      int row = b*NPTS + L.w.nbrS[tid];
      L.w.Hs[tid*69+64] = pos[(size_t)row*3+0] - cx;
      L.w.Hs[tid*69+65] = pos[(size_t)row*3+1] - cy;
      L.w.Hs[tid*69+66] = pos[(size_t)row*3+2] - cz;
    }
    __syncthreads();

    // ---- GEMM: thread = (edge, col of 16 ch); W via wave-uniform SCALAR loads (SMEM pipe)
    const int edge = tid & 63;
    const int col  = __builtin_amdgcn_readfirstlane(tid >> 6);
    float acc[16];
    #pragma unroll
    for (int j = 0; j < 16; ++j) acc[j] = 0.f;
    const float* hrow = L.w.Hs + edge*69;
    const float* wcol = W1 + col*16;
    for (int k = 0; k < K1; ++k) {
      float hk = hrow[k];
      const float4* w4 = (const float4*)(wcol + k*CH1);
      #pragma unroll
      for (int q = 0; q < 4; ++q) {
        float4 wv = w4[q];
        acc[q*4+0] = fmaf(hk, wv.x, acc[q*4+0]);
        acc[q*4+1] = fmaf(hk, wv.y, acc[q*4+1]);
        acc[q*4+2] = fmaf(hk, wv.z, acc[q*4+2]);
        acc[q*4+3] = fmaf(hk, wv.w, acc[q*4+3]);
      }
    }
    const bool valid = edge < c;
    #pragma unroll
    for (int j = 0; j < 16; ++j) acc[j] = valid ? acc[j] : 0.f;
    u32* dst = (u32*)(y1g + ((size_t)bm*64 + edge)*CH1 + col*16);
    #pragma unroll
    for (int j = 0; j < 8; ++j)
      dst[j] = (u32)f2bf(acc[2*j]) | ((u32)f2bf(acc[2*j+1]) << 16);
    #pragma unroll
    for (int j = 0; j < 16; ++j) {
      float s = wsum(acc[j]);
      float q = wsum(acc[j]*acc[j]);
      if (edge == 0) { L.w.red[col][j] = s; L.w.red[col][16+j] = q; }
    }
    __syncthreads();
    const int slot = bm & (NSLOT-1);
    if (tid < 64)  atomicAdd(&Spart[slot*256 + tid], L.w.red[tid>>4][tid&15]);
    else if (tid < 128) {
      int cc = tid - 64;
      atomicAdd(&Spart[slot*256 + 128 + cc], L.w.red[cc>>4][16 + (cc&15)]);
    }
    // top-of-loop __syncthreads() isolates this task's LDS reads from next task's writes
  }
}

// ---------------------------------------------------------------- stage 2: relu(bn1(y1)) @ W2
__global__ __launch_bounds__(256) void k_s2(const u16* __restrict__ y1g,
                                            const float* __restrict__ SC,
                                            const float* __restrict__ W2,
                                            const int* __restrict__ cntpc,
                                            float* __restrict__ Spart,
                                            u16* __restrict__ y2g) {
  __shared__ float Hs[64*65];
  __shared__ float ABs[128];
  __shared__ float red[4][32];
  __shared__ int   cntS;
  const int tid = threadIdx.x, bm = blockIdx.x;
  if (tid == 0) cntS = cntpc[bm];
  if (tid < 128) ABs[tid] = SC[tid];            // A1(64) B1(64)
  __syncthreads();
  {
    const u32* yt = (const u32*)y1g + (size_t)bm*2048;  // 64 edges * 32 u32
    #pragma unroll
    for (int rep = 0; rep < 8; ++rep) {
      int g = rep*256 + tid;
      int e = g >> 5, c2 = g & 31, ch = c2*2;
      u32 v = yt[g];
      float lo = fmaxf(fmaf(bf2f((u16)(v & 0xffff)), ABs[ch],   ABs[64+ch]),   0.f);
      float hi = fmaxf(fmaf(bf2f((u16)(v >> 16)),    ABs[ch+1], ABs[64+ch+1]), 0.f);
      Hs[e*65 + ch] = lo; Hs[e*65 + ch + 1] = hi;
    }
  }
  __syncthreads();

  const int edge = tid & 63;
  const int col  = __builtin_amdgcn_readfirstlane(tid >> 6);
  float acc[16];
  #pragma unroll
  for (int j = 0; j < 16; ++j) acc[j] = 0.f;
  const float* hrow = Hs + edge*65;
  const float* wcol = W2 + col*16;
  for (int k = 0; k < CH1; ++k) {
    float hk = hrow[k];
    const float4* w4 = (const float4*)(wcol + k*CH2);
    #pragma unroll
    for (int q = 0; q < 4; ++q) {
      float4 wv = w4[q];
      acc[q*4+0] = fmaf(hk, wv.x, acc[q*4+0]);
      acc[q*4+1] = fmaf(hk, wv.y, acc[q*4+1]);
      acc[q*4+2] = fmaf(hk, wv.z, acc[q*4+2]);
      acc[q*4+3] = fmaf(hk, wv.w, acc[q*4+3]);
    }
  }
  const bool valid = edge < cntS;
  #pragma unroll
  for (int j = 0; j < 16; ++j) acc[j] = valid ? acc[j] : 0.f;
  u32* dst = (u32*)(y2g + ((size_t)bm*64 + edge)*CH2 + col*16);
  #pragma unroll
  for (int j = 0; j < 8; ++j)
    dst[j] = (u32)f2bf(acc[2*j]) | ((u32)f2bf(acc[2*j+1]) << 16);
  #pragma unroll
  for (int j = 0; j < 16; ++j) {
    float s = wsum(acc[j]);
    float q = wsum(acc[j]*acc[j]);
    if (edge == 0) { red[col][j] = s; red[col][16+j] = q; }
  }
  __syncthreads();
  const int slot = bm & (NSLOT-1);
  if (tid < 64)  atomicAdd(&Spart[slot*256 + tid], red[tid>>4][tid&15]);
  else if (tid < 128) {
    int c = tid - 64;
    atomicAdd(&Spart[slot*256 + 128 + c], red[c>>4][16 + (c&15)]);
  }
}

// ---------------------------------------------------------------- stage 3: relu(bn2(y2)) @ W3
template<bool STORE>
__global__ __launch_bounds__(256) void k_s3(const u16* __restrict__ y2g,
                                            const float* __restrict__ SC,
                                            const float* __restrict__ W3,
                                            const int* __restrict__ cntpc,
                                            float* __restrict__ Spart,
                                            u16* __restrict__ y3g,
                                            float* __restrict__ out0) {
  __shared__ float Hs[64*65];
  __shared__ float ABs[128];
  __shared__ float red[4][64];
  __shared__ int   cntS;
  const int tid = threadIdx.x, bm = blockIdx.x;
  if (tid == 0) cntS = cntpc[bm];
  if (tid < 128) ABs[tid] = SC[128 + tid];      // A2(64) B2(64)
  __syncthreads();
  {
    const u32* yt = (const u32*)y2g + (size_t)bm*2048;
    #pragma unroll
    for (int rep = 0; rep < 8; ++rep) {
      int g = rep*256 + tid;
      int e = g >> 5, c2 = g & 31, ch = c2*2;
      u32 v = yt[g];
      float lo = fmaxf(fmaf(bf2f((u16)(v & 0xffff)), ABs[ch],   ABs[64+ch]),   0.f);
      float hi = fmaxf(fmaf(bf2f((u16)(v >> 16)),    ABs[ch+1], ABs[64+ch+1]), 0.f);
      Hs[e*65 + ch] = lo; Hs[e*65 + ch + 1] = hi;
    }
  }
  __syncthreads();

  const int edge = tid & 63;
  const int col  = __builtin_amdgcn_readfirstlane(tid >> 6);  // owns 32 of 128 ch
  float acc[32];
  #pragma unroll
  for (int j = 0; j < 32; ++j) acc[j] = 0.f;
  const float* hrow = Hs + edge*65;
  const float* wcol = W3 + col*32;
  for (int k = 0; k < CH2; ++k) {
    float hk = hrow[k];
    const float4* w4 = (const float4*)(wcol + k*CH3);
    #pragma unroll
    for (int q = 0; q < 8; ++q) {
      float4 wv = w4[q];
      acc[q*4+0] = fmaf(hk, wv.x, acc[q*4+0]);
      acc[q*4+1] = fmaf(hk, wv.y, acc[q*4+1]);
      acc[q*4+2] = fmaf(hk, wv.z, acc[q*4+2]);
      acc[q*4+3] = fmaf(hk, wv.w, acc[q*4+3]);
    }
  }
  const bool valid = edge < cntS;
  #pragma unroll
  for (int j = 0; j < 32; ++j) acc[j] = valid ? acc[j] : 0.f;
  if constexpr (STORE) {
    u32* dst = (u32*)(y3g + ((size_t)bm*64 + edge)*CH3 + col*32);
    #pragma unroll
    for (int j = 0; j < 16; ++j)
      dst[j] = (u32)f2bf(acc[2*j]) | ((u32)f2bf(acc[2*j+1]) << 16);
  }
  #pragma unroll
  for (int j = 0; j < 32; ++j) {
    float s = wsum(acc[j]);
    float q = wsum(acc[j]*acc[j]);
    if (edge == 0) { red[col][j] = s; red[col][32+j] = q; }
  }
  __syncthreads();
  const int slot = bm & (NSLOT-1);
  if (tid < 128) atomicAdd(&Spart[slot*256 + tid], red[tid>>5][tid&31]);
  else {
    int c = tid - 128;
    atomicAdd(&Spart[slot*256 + 128 + c], red[c>>5][32 + (c&31)]);
  }
}

// ---------------------------------------------------------------- stage 4A: bn3+relu+maxpool from stored y3
__global__ __launch_bounds__(128) void k_s4(const u16* __restrict__ y3g,
                                            const float* __restrict__ SC,
                                            const int* __restrict__ cntpc,
                                            float* __restrict__ out0) {
  const int tid = threadIdx.x, bm = blockIdx.x;
  const int cnt = cntpc[bm];
  const float a = SC[256 + tid], b = SC[384 + tid];
  const u16* yr = y3g + (size_t)bm*64*CH3 + tid;
  float mx = -1e30f;
  for (int e = 0; e < cnt; ++e) {
    float v = bf2f(yr[e*CH3]);
    mx = fmaxf(mx, fmaxf(fmaf(v, a, b), 0.f));
  }
  out0[(size_t)bm*CH3 + tid] = mx;
}

// ---------------------------------------------------------------- stage 4B (fallback): recompute y3 from y2
__global__ __launch_bounds__(256) void k_s4r(const u16* __restrict__ y2g,
                                             const float* __restrict__ SC,
                                             const float* __restrict__ W3,
                                             const int* __restrict__ cntpc,
                                             float* __restrict__ out0) {
  __shared__ float Hs[64*65];
  __shared__ float ABs[128];
  __shared__ float AB3[256];
  __shared__ int   cntS;
  const int tid = threadIdx.x, bm = blockIdx.x;
  if (tid == 0) cntS = cntpc[bm];
  if (tid < 128) ABs[tid] = SC[128 + tid];
  ((float*)AB3)[tid] = SC[256 + tid];   // A3(128) B3(128)
  __syncthreads();
  {
    const u32* yt = (const u32*)y2g + (size_t)bm*2048;
    #pragma unroll
    for (int rep = 0; rep < 8; ++rep) {
      int g = rep*256 + tid;
      int e = g >> 5, c2 = g & 31, ch = c2*2;
      u32 v = yt[g];
      float lo = fmaxf(fmaf(bf2f((u16)(v & 0xffff)), ABs[ch],   ABs[64+ch]),   0.f);
      float hi = fmaxf(fmaf(bf2f((u16)(v >> 16)),    ABs[ch+1], ABs[64+ch+1]), 0.f);
      Hs[e*65 + ch] = lo; Hs[e*65 + ch + 1] = hi;
    }
  }
  __syncthreads();
  const int edge = tid & 63;
  const int col  = __builtin_amdgcn_readfirstlane(tid >> 6);
  float acc[32];
  #pragma unroll
  for (int j = 0; j < 32; ++j) acc[j] = 0.f;
  const float* hrow = Hs + edge*65;
  const float* wcol = W3 + col*32;
  for (int k = 0; k < CH2; ++k) {
    float hk = hrow[k];
    const float4* w4 = (const float4*)(wcol + k*CH3);
    #pragma unroll
    for (int q = 0; q < 8; ++q) {
      float4 wv = w4[q];
      acc[q*4+0] = fmaf(hk, wv.x, acc[q*4+0]);
      acc[q*4+1] = fmaf(hk, wv.y, acc[q*4+1]);
      acc[q*4+2] = fmaf(hk, wv.z, acc[q*4+2]);
      acc[q*4+3] = fmaf(hk, wv.w, acc[q*4+3]);
    }
  }
  const bool valid = edge < cntS;
  #pragma unroll
  for (int j = 0; j < 32; ++j) {
    int ch = col*32 + j;
    float h = fmaxf(fmaf(acc[j], AB3[ch], AB3[128+ch]), 0.f);
    float mx = wmax(valid ? h : -1e30f);
    if (edge == 0) out0[(size_t)bm*CH3 + ch] = mx;
  }
}

// ---------------------------------------------------------------- finalize
__global__ void k_finalize(const float* __restrict__ Spart,
                           const float* __restrict__ g, const float* __restrict__ bb,
                           const int* __restrict__ cnt_total,
                           float* __restrict__ Aout, float* __restrict__ Bout, int C) {
  int c = threadIdx.x;
  if (c < C) {
    float s = 0.f, q = 0.f;
    for (int sl = 0; sl < NSLOT; ++sl) {
      s += Spart[sl*256 + c];
      q += Spart[sl*256 + 128 + c];
    }
    float n = (float)(*cnt_total); if (n < 1.f) n = 1.f;
    float mu  = s / n;
    float var = q / n - mu*mu; if (var < 0.f) var = 0.f;
    float inv = 1.0f / sqrtf(var + 1e-5f);
    float a = g[c] * inv;
    Aout[c] = a;
    Bout[c] = bb[c] - mu*a;
  }
}

// ---------------------------------------------------------------- host
extern "C" void kernel_launch(void* const* d_in, const int* in_sizes, int n_in,
                              void* d_out, int out_size, void* d_ws, size_t ws_size,
                              hipStream_t stream) {
  (void)in_sizes; (void)n_in; (void)out_size;
  const float* x   = (const float*)d_in[0];
  const float* pos = (const float*)d_in[1];
  const float* W1  = (const float*)d_in[3];
  const float* g1  = (const float*)d_in[4];
  const float* b1  = (const float*)d_in[5];
  const float* W2  = (const float*)d_in[6];
  const float* g2  = (const float*)d_in[7];
  const float* b2  = (const float*)d_in[8];
  const float* W3  = (const float*)d_in[9];
  const float* g3  = (const float*)d_in[10];
  const float* b3  = (const float*)d_in[11];

  float* out0     = (float*)d_out;
  float* out_cent = out0 + (size_t)NB*MC*CH3;
  float* out_bsel = out_cent + (size_t)NB*MC*3;

  char* base = (char*)d_ws;
  size_t off = 0;
  auto carve = [&](size_t bytes) -> char* {
    char* p = base + off;
    off = (off + bytes + 255) & ~(size_t)255;
    return p;
  };
  float* centf = (float*)carve(sizeof(float)*NB*MC*3);
  int*   cntpc = (int*)  carve(sizeof(int)*NB*MC);
  char*  zeroblk = carve(256 + 3*NSLOT*256*sizeof(float));
  int*   cnt_total = (int*)zeroblk;
  int*   taskctr   = cnt_total + 1;
  int*   progress  = cnt_total + 2;    // 8 ints
  float* Sp1 = (float*)(zeroblk + 256);
  float* Sp2 = Sp1 + NSLOT*256;
  float* Sp3 = Sp2 + NSLOT*256;
  float* SC = (float*)carve(512*sizeof(float));  // A1 B1 A2 B2 A3(128) B3(128)
  u16* y1g = (u16*)carve((size_t)NE*CH1*2);
  u16* y2g = (u16*)carve((size_t)NE*CH2*2);
  u16* y3g = (u16*)carve((size_t)NE*CH3*2);
  bool have_y3 = (ws_size >= off);

  hipMemsetAsync(zeroblk, 0, 256 + 3*NSLOT*256*sizeof(float), stream);
  k_front<<<NBLK, 256, 0, stream>>>(x, pos, centf, out_cent, out_bsel,
                                    W1, Sp1, y1g, cntpc, cnt_total, progress, taskctr);
  k_finalize<<<1, 128, 0, stream>>>(Sp1, g1, b1, cnt_total, SC + 0,   SC + 64,  CH1);
  dim3 sg(NB*MC), sb(256);
  k_s2<<<sg, sb, 0, stream>>>(y1g, SC, W2, cntpc, Sp2, y2g);
  k_finalize<<<1, 128, 0, stream>>>(Sp2, g2, b2, cnt_total, SC + 128, SC + 192, CH2);
  if (have_y3) {
    k_s3<true><<<sg, sb, 0, stream>>>(y2g, SC, W3, cntpc, Sp3, y3g, out0);
    k_finalize<<<1, 128, 0, stream>>>(Sp3, g3, b3, cnt_total, SC + 256, SC + 384, CH3);
    k_s4<<<sg, 128, 0, stream>>>(y3g, SC, cntpc, out0);
  } else {
    k_s3<false><<<sg, sb, 0, stream>>>(y2g, SC, W3, cntpc, Sp3, y3g, out0);
    k_finalize<<<1, 128, 0, stream>>>(Sp3, g3, b3, cnt_total, SC + 256, SC + 384, CH3);
    k_s4r<<<sg, sb, 0, stream>>>(y2g, SC, W3, cntpc, out0);
  }
}

// Round 10
// 1376.927 us; speedup vs baseline: 1.1073x; 1.1073x over previous
//
#include <hip/hip_runtime.h>
#include <stdint.h>

#define NB   8
#define NPTS 4096
#define CINV 64
#define MC   1024
#define KNB  64
#define NE   (NB*MC*KNB)
#define K1   67
#define CH1  64
#define CH2  64
#define CH3  128
#define NSLOT 64
#define CAP  2048
#define NTASK (NB*MC)
#define NBLK 256      // == #CUs; static 53.8KB + dynamic 30KB LDS -> exactly 1 block/CU
#define DYNLDS 30720

typedef unsigned short u16;
typedef unsigned int   u32;
typedef unsigned long long u64;

static __device__ __forceinline__ float bf2f(u16 b){ return __uint_as_float(((u32)b)<<16); }
static __device__ __forceinline__ u16  f2bf(float f){
  u32 u = __float_as_uint(f);
  return (u16)((u + 0x7fffu + ((u>>16)&1u)) >> 16);
}
// Exact replica of reference distance: square each diff, sum as (x+y)+z, NO fma contraction.
static __device__ __forceinline__ float d2ref(float ax,float ay,float az,
                                              float bx,float by,float bz){
  float dx = ax-bx, dy = ay-by, dz = az-bz;
  return __fadd_rn(__fadd_rn(__fmul_rn(dx,dx), __fmul_rn(dy,dy)), __fmul_rn(dz,dz));
}
static __device__ __forceinline__ float wsum(float v){
  #pragma unroll
  for (int off = 32; off > 0; off >>= 1) v += __shfl_xor(v, off);
  return v;
}
static __device__ __forceinline__ float wmax(float v){
  #pragma unroll
  for (int off = 32; off > 0; off >>= 1) v = fmaxf(v, __shfl_xor(v, off));
  return v;
}
// One DPP max step: v = max(v, dpp_shuffle(v)). Pure VALU (no DS pipe).
template<int CTRL, int RMASK>
static __device__ __forceinline__ float dppmaxstep(float v){
  int t = __builtin_amdgcn_update_dpp(__float_as_int(v), __float_as_int(v),
                                      CTRL, RMASK, 0xF, false);
  return fmaxf(v, __int_as_float(t));
}
// Full wave64 max -> broadcast via readlane(63).
static __device__ __forceinline__ float wavemax_dpp(float v){
  v = dppmaxstep<0xB1, 0xF>(v);
  v = dppmaxstep<0x4E, 0xF>(v);
  v = dppmaxstep<0x141,0xF>(v);
  v = dppmaxstep<0x140,0xF>(v);
  v = dppmaxstep<0x142,0xA>(v);
  v = dppmaxstep<0x143,0xC>(v);
  return __int_as_float(__builtin_amdgcn_readlane(__float_as_int(v), 63));
}

// ---------------------------------------------------------------- fused front kernel
struct FpsL {
  float px[NPTS], py[NPTS], pz[NPTS];
  int   sIdx[MC];
  float4 cand[16];   // (d,x,y,z), double-buffered 2x8
  int    cIv[16];
  float4 cbuf[16];   // centroid staging: flush 16 rows per tile to global
};
struct WkL {
  u64   keys[CAP];        // ball-query sort keys
  float Hs[64*69];        // stage-1 H tile (odd pitch)
  int   nbrS[64];
  float red[8][16];
  float cxyz[3];
  int   scnt;
  int   task;
};
union FrontL { FpsL f; WkL w; };

__global__ __launch_bounds__(512) void k_front(const float* __restrict__ x,
                                               const float* __restrict__ pos,
                                               float* __restrict__ centf,
                                               float* __restrict__ out_cent,
                                               float* __restrict__ out_bsel,
                                               const float* __restrict__ W1,
                                               float* __restrict__ Spart,
                                               u16* __restrict__ y1g,
                                               int* __restrict__ cntpc,
                                               int* __restrict__ cnt_total,
                                               int* __restrict__ progress,
                                               int* __restrict__ taskctr) {
  __shared__ FrontL L;
  const int tid = threadIdx.x;

  if (blockIdx.x < NB) {
    // ============ FPS producer: 8 waves (2/SIMD, latency hiding), 1 barrier/iter
    const int b = blockIdx.x;
    for (int i = tid; i < NPTS; i += 512) {
      size_t o = ((size_t)b*NPTS + i)*3;
      L.f.px[i] = pos[o]; L.f.py[i] = pos[o+1]; L.f.pz[i] = pos[o+2];
    }
    float qx0 = 0.f, qy0 = 0.f, qz0 = 0.f;
    __syncthreads();

    float cxr[8], cyr[8], czr[8], dist[8];
    #pragma unroll
    for (int j = 0; j < 8; ++j) {
      int p = tid*8 + j;
      cxr[j] = L.f.px[p]; cyr[j] = L.f.py[p]; czr[j] = L.f.pz[p];
      dist[j] = 1e10f;
    }
    const int lane = tid & 63, w = tid >> 6;
    float qx = L.f.px[0], qy = L.f.py[0], qz = L.f.pz[0];
    (void)qx0; (void)qy0; (void)qz0;
    if (tid == 0) {
      L.f.sIdx[0] = 0;
      L.f.cbuf[0] = make_float4(qx, qy, qz, 0.f);
    }

    for (int it = 1; it < MC; ++it) {
      float bv = -1.f, bx = 0.f, by = 0.f, bz = 0.f; int bi = 0;
      #pragma unroll
      for (int j = 0; j < 8; ++j) {
        float d  = d2ref(cxr[j], cyr[j], czr[j], qx, qy, qz);
        float nd = fminf(dist[j], d);
        dist[j] = nd;
        if (nd > bv) { bv = nd; bi = tid*8 + j; bx = cxr[j]; by = cyr[j]; bz = czr[j]; }
      }
      // in-wave max (DPP, VALU-only); lowest winning lane = lowest index
      float gmax = wavemax_dpp(bv);
      u64 mm = __ballot(bv == gmax);
      int wl = __ffsll((unsigned long long)mm) - 1;
      const int base = (it & 1) * 8;
      if (lane == wl) {
        L.f.cand[base + w] = make_float4(gmax, bx, by, bz);
        L.f.cIv[base + w]  = bi;
      }
      __syncthreads();
      // every wave resolves the 8 candidates redundantly (no second barrier)
      float4 cq = L.f.cand[base + (lane & 7)];
      float dm = cq.x;
      dm = dppmaxstep<0xB1, 0xF>(dm);    // xor1
      dm = dppmaxstep<0x4E, 0xF>(dm);    // xor2
      dm = dppmaxstep<0x141,0xF>(dm);    // half-mirror -> max over each 8-group
      u64 m2 = __ballot(cq.x == dm);
      int wc = (__ffsll((unsigned long long)m2) - 1) & 7;  // lowest cand = lowest wave = lowest idx
      float4 nq = L.f.cand[base + wc];   // broadcast LDS read of the winner
      qx = nq.y; qy = nq.z; qz = nq.w;
      // flush PREVIOUS 16-row tile (rows it-16..it-1) then release-publish progress
      if ((it & 15) == 0 && tid < 16) {
        int mrow = it - 16 + tid;
        float4 cc = L.f.cbuf[tid];
        int r = b*MC + mrow;
        centf[r*3+0] = cc.x; centf[r*3+1] = cc.y; centf[r*3+2] = cc.z;
        if (tid == 0)
          __hip_atomic_store(progress + b, it, __ATOMIC_RELEASE, __HIP_MEMORY_SCOPE_AGENT);
      }
      if (tid == 0) {
        L.f.sIdx[it] = L.f.cIv[base + wc];
        L.f.cbuf[it & 15] = make_float4(qx, qy, qz, 0.f);
      }
    }
    __syncthreads();
    // final tile flush (rows MC-16..MC-1) + progress = MC
    if (tid < 16) {
      int mrow = MC - 16 + tid;
      float4 cc = L.f.cbuf[tid];
      int r = b*MC + mrow;
      centf[r*3+0] = cc.x; centf[r*3+1] = cc.y; centf[r*3+2] = cc.z;
      if (tid == 0)
        __hip_atomic_store(progress + b, MC, __ATOMIC_RELEASE, __HIP_MEMORY_SCOPE_AGENT);
    }
    // epilogue: out_cent / out_bsel from sIdx (off the critical path)
    for (int m2_ = tid; m2_ < MC; m2_ += 512) {
      int i = L.f.sIdx[m2_];
      int r = b*MC + m2_;
      out_cent[r*3+0] = L.f.px[i]; out_cent[r*3+1] = L.f.py[i]; out_cent[r*3+2] = L.f.pz[i];
      out_bsel[r] = (float)b;
    }
    return;
  }

  // ============ persistent workers: ball query + stage-1 per centroid (512 thr)
  for (;;) {
    if (tid == 0) {
      int t = atomicAdd(taskctr, 1);
      L.w.task = t;
      if (t < NTASK) {
        int m = t >> 3, b = t & 7;
        while (__hip_atomic_load(progress + b, __ATOMIC_ACQUIRE, __HIP_MEMORY_SCOPE_AGENT) < m + 1)
          __builtin_amdgcn_s_sleep(8);
        int bm = b*MC + m;
        L.w.cxyz[0] = __hip_atomic_load(centf + bm*3 + 0, __ATOMIC_RELAXED, __HIP_MEMORY_SCOPE_AGENT);
        L.w.cxyz[1] = __hip_atomic_load(centf + bm*3 + 1, __ATOMIC_RELAXED, __HIP_MEMORY_SCOPE_AGENT);
        L.w.cxyz[2] = __hip_atomic_load(centf + bm*3 + 2, __ATOMIC_RELAXED, __HIP_MEMORY_SCOPE_AGENT);
      }
      L.w.scnt = 0;
    }
    __syncthreads();
    const int t = L.w.task;
    if (t >= NTASK) return;
    const int m = t >> 3, b = t & 7, bm = b*MC + m;
    const float cx = L.w.cxyz[0], cy = L.w.cxyz[1], cz = L.w.cxyz[2];

    // ---- ball query (exact ref semantics)
    for (int i = tid; i < NPTS; i += 512) {
      size_t o = ((size_t)b*NPTS + i)*3;
      float d = d2ref(cx, cy, cz, pos[o], pos[o+1], pos[o+2]);
      if (d <= 0.04f) {
        int p = atomicAdd(&L.w.scnt, 1);
        if (p < CAP) L.w.keys[p] = ((u64)__float_as_uint(d) << 32) | (u32)i;
      }
    }
    __syncthreads();
    int n = L.w.scnt; if (n > CAP) n = CAP;
    int P = 64; while (P < n) P <<= 1;
    for (int i = n + tid; i < P; i += 512) L.w.keys[i] = ~0ull;
    __syncthreads();
    for (int ks = 2; ks <= P; ks <<= 1)
      for (int js = ks >> 1; js > 0; js >>= 1) {
        for (int i = tid; i < P; i += 512) {
          int l = i ^ js;
          if (l > i) {
            u64 a = L.w.keys[i], c = L.w.keys[l];
            bool up = ((i & ks) == 0);
            if ((a > c) == up) { L.w.keys[i] = c; L.w.keys[l] = a; }
          }
        }
        __syncthreads();
      }
    const int c = n < KNB ? n : KNB;
    if (tid < KNB) L.w.nbrS[tid] = (tid < c) ? (int)(u32)(L.w.keys[tid] & 0xffffffffu) : 0;
    if (tid == 0) { cntpc[bm] = c; atomicAdd(cnt_total, c); }
    __syncthreads();

    // ---- stage-1: H = [x_j, p_j - c_i] (64x67) staged in LDS
    {
      const int ge = tid >> 3, qb = tid & 7;
      const float4* xr = (const float4*)(x + ((size_t)(b*NPTS + L.w.nbrS[ge]))*CINV);
      #pragma unroll
      for (int rep = 0; rep < 2; ++rep) {
        int q = qb + rep*8;
        float4 v = xr[q];
        float* d = L.w.Hs + ge*69 + q*4;
        d[0] = v.x; d[1] = v.y; d[2] = v.z; d[3] = v.w;
      }
    }
    if (tid < 64) {
      int row = b*NPTS + L.w.nbrS[tid];
      L.w.Hs[tid*69+64] = pos[(size_t)row*3+0] - cx;
      L.w.Hs[tid*69+65] = pos[(size_t)row*3+1] - cy;
      L.w.Hs[tid*69+66] = pos[(size_t)row*3+2] - cz;
    }
    __syncthreads();

    // ---- GEMM: thread = (edge, col of 8 ch); W via wave-uniform SCALAR loads
    const int edge = tid & 63;
    const int col  = __builtin_amdgcn_readfirstlane(tid >> 6);  // 0..7
    float acc[8];
    #pragma unroll
    for (int j = 0; j < 8; ++j) acc[j] = 0.f;
    const float* hrow = L.w.Hs + edge*69;
    const float* wcol = W1 + col*8;
    for (int k = 0; k < K1; ++k) {
      float hk = hrow[k];
      const float4* w4 = (const float4*)(wcol + k*CH1);
      float4 a = w4[0], bq = w4[1];
      acc[0] = fmaf(hk, a.x,  acc[0]); acc[1] = fmaf(hk, a.y,  acc[1]);
      acc[2] = fmaf(hk, a.z,  acc[2]); acc[3] = fmaf(hk, a.w,  acc[3]);
      acc[4] = fmaf(hk, bq.x, acc[4]); acc[5] = fmaf(hk, bq.y, acc[5]);
      acc[6] = fmaf(hk, bq.z, acc[6]); acc[7] = fmaf(hk, bq.w, acc[7]);
    }
    const bool valid = edge < c;
    #pragma unroll
    for (int j = 0; j < 8; ++j) acc[j] = valid ? acc[j] : 0.f;
    u32* dst = (u32*)(y1g + ((size_t)bm*64 + edge)*CH1 + col*8);
    #pragma unroll
    for (int j = 0; j < 4; ++j)
      dst[j] = (u32)f2bf(acc[2*j]) | ((u32)f2bf(acc[2*j+1]) << 16);
    #pragma unroll
    for (int j = 0; j < 8; ++j) {
      float s = wsum(acc[j]);
      float q = wsum(acc[j]*acc[j]);
      if (edge == 0) { L.w.red[col][j] = s; L.w.red[col][8+j] = q; }
    }
    __syncthreads();
    const int slot = bm & (NSLOT-1);
    if (tid < 64)  atomicAdd(&Spart[slot*256 + tid], L.w.red[tid>>3][tid&7]);
    else if (tid < 128) {
      int cc = tid - 64;
      atomicAdd(&Spart[slot*256 + 128 + cc], L.w.red[cc>>3][8 + (cc&7)]);
    }
    // top-of-loop __syncthreads() isolates this task's LDS reads from next task's writes
  }
}

// ---------------------------------------------------------------- stage 2: relu(bn1(y1)) @ W2
__global__ __launch_bounds__(256) void k_s2(const u16* __restrict__ y1g,
                                            const float* __restrict__ SC,
                                            const float* __restrict__ W2,
                                            const int* __restrict__ cntpc,
                                            float* __restrict__ Spart,
                                            u16* __restrict__ y2g) {
  __shared__ float Hs[64*65];
  __shared__ float ABs[128];
  __shared__ float red[4][32];
  __shared__ int   cntS;
  const int tid = threadIdx.x, bm = blockIdx.x;
  if (tid == 0) cntS = cntpc[bm];
  if (tid < 128) ABs[tid] = SC[tid];            // A1(64) B1(64)
  __syncthreads();
  {
    const u32* yt = (const u32*)y1g + (size_t)bm*2048;  // 64 edges * 32 u32
    #pragma unroll
    for (int rep = 0; rep < 8; ++rep) {
      int g = rep*256 + tid;
      int e = g >> 5, c2 = g & 31, ch = c2*2;
      u32 v = yt[g];
      float lo = fmaxf(fmaf(bf2f((u16)(v & 0xffff)), ABs[ch],   ABs[64+ch]),   0.f);
      float hi = fmaxf(fmaf(bf2f((u16)(v >> 16)),    ABs[ch+1], ABs[64+ch+1]), 0.f);
      Hs[e*65 + ch] = lo; Hs[e*65 + ch + 1] = hi;
    }
  }
  __syncthreads();

  const int edge = tid & 63;
  const int col  = __builtin_amdgcn_readfirstlane(tid >> 6);
  float acc[16];
  #pragma unroll
  for (int j = 0; j < 16; ++j) acc[j] = 0.f;
  const float* hrow = Hs + edge*65;
  const float* wcol = W2 + col*16;
  for (int k = 0; k < CH1; ++k) {
    float hk = hrow[k];
    const float4* w4 = (const float4*)(wcol + k*CH2);
    #pragma unroll
    for (int q = 0; q < 4; ++q) {
      float4 wv = w4[q];
      acc[q*4+0] = fmaf(hk, wv.x, acc[q*4+0]);
      acc[q*4+1] = fmaf(hk, wv.y, acc[q*4+1]);
      acc[q*4+2] = fmaf(hk, wv.z, acc[q*4+2]);
      acc[q*4+3] = fmaf(hk, wv.w, acc[q*4+3]);
    }
  }
  const bool valid = edge < cntS;
  #pragma unroll
  for (int j = 0; j < 16; ++j) acc[j] = valid ? acc[j] : 0.f;
  u32* dst = (u32*)(y2g + ((size_t)bm*64 + edge)*CH2 + col*16);
  #pragma unroll
  for (int j = 0; j < 8; ++j)
    dst[j] = (u32)f2bf(acc[2*j]) | ((u32)f2bf(acc[2*j+1]) << 16);
  #pragma unroll
  for (int j = 0; j < 16; ++j) {
    float s = wsum(acc[j]);
    float q = wsum(acc[j]*acc[j]);
    if (edge == 0) { red[col][j] = s; red[col][16+j] = q; }
  }
  __syncthreads();
  const int slot = bm & (NSLOT-1);
  if (tid < 64)  atomicAdd(&Spart[slot*256 + tid], red[tid>>4][tid&15]);
  else if (tid < 128) {
    int c = tid - 64;
    atomicAdd(&Spart[slot*256 + 128 + c], red[c>>4][16 + (c&15)]);
  }
}

// ---------------------------------------------------------------- stage 3: relu(bn2(y2)) @ W3
template<bool STORE>
__global__ __launch_bounds__(256) void k_s3(const u16* __restrict__ y2g,
                                            const float* __restrict__ SC,
                                            const float* __restrict__ W3,
                                            const int* __restrict__ cntpc,
                                            float* __restrict__ Spart,
                                            u16* __restrict__ y3g,
                                            float* __restrict__ out0) {
  __shared__ float Hs[64*65];
  __shared__ float ABs[128];
  __shared__ float red[4][64];
  __shared__ int   cntS;
  const int tid = threadIdx.x, bm = blockIdx.x;
  if (tid == 0) cntS = cntpc[bm];
  if (tid < 128) ABs[tid] = SC[128 + tid];      // A2(64) B2(64)
  __syncthreads();
  {
    const u32* yt = (const u32*)y2g + (size_t)bm*2048;
    #pragma unroll
    for (int rep = 0; rep < 8; ++rep) {
      int g = rep*256 + tid;
      int e = g >> 5, c2 = g & 31, ch = c2*2;
      u32 v = yt[g];
      float lo = fmaxf(fmaf(bf2f((u16)(v & 0xffff)), ABs[ch],   ABs[64+ch]),   0.f);
      float hi = fmaxf(fmaf(bf2f((u16)(v >> 16)),    ABs[ch+1], ABs[64+ch+1]), 0.f);
      Hs[e*65 + ch] = lo; Hs[e*65 + ch + 1] = hi;
    }
  }
  __syncthreads();

  const int edge = tid & 63;
  const int col  = __builtin_amdgcn_readfirstlane(tid >> 6);  // owns 32 of 128 ch
  float acc[32];
  #pragma unroll
  for (int j = 0; j < 32; ++j) acc[j] = 0.f;
  const float* hrow = Hs + edge*65;
  const float* wcol = W3 + col*32;
  for (int k = 0; k < CH2; ++k) {
    float hk = hrow[k];
    const float4* w4 = (const float4*)(wcol + k*CH3);
    #pragma unroll
    for (int q = 0; q < 8; ++q) {
      float4 wv = w4[q];
      acc[q*4+0] = fmaf(hk, wv.x, acc[q*4+0]);
      acc[q*4+1] = fmaf(hk, wv.y, acc[q*4+1]);
      acc[q*4+2] = fmaf(hk, wv.z, acc[q*4+2]);
      acc[q*4+3] = fmaf(hk, wv.w, acc[q*4+3]);
    }
  }
  const bool valid = edge < cntS;
  #pragma unroll
  for (int j = 0; j < 32; ++j) acc[j] = valid ? acc[j] : 0.f;
  if constexpr (STORE) {
    u32* dst = (u32*)(y3g + ((size_t)bm*64 + edge)*CH3 + col*32);
    #pragma unroll
    for (int j = 0; j < 16; ++j)
      dst[j] = (u32)f2bf(acc[2*j]) | ((u32)f2bf(acc[2*j+1]) << 16);
  }
  #pragma unroll
  for (int j = 0; j < 32; ++j) {
    float s = wsum(acc[j]);
    float q = wsum(acc[j]*acc[j]);
    if (edge == 0) { red[col][j] = s; red[col][32+j] = q; }
  }
  __syncthreads();
  const int slot = bm & (NSLOT-1);
  if (tid < 128) atomicAdd(&Spart[slot*256 + tid], red[tid>>5][tid&31]);
  else {
    int c = tid - 128;
    atomicAdd(&Spart[slot*256 + 128 + c], red[c>>5][32 + (c&31)]);
  }
}

// ---------------------------------------------------------------- stage 4A: bn3+relu+maxpool from stored y3
__global__ __launch_bounds__(128) void k_s4(const u16* __restrict__ y3g,
                                            const float* __restrict__ SC,
                                            const int* __restrict__ cntpc,
                                            float* __restrict__ out0) {
  const int tid = threadIdx.x, bm = blockIdx.x;
  const int cnt = cntpc[bm];
  const float a = SC[256 + tid], b = SC[384 + tid];
  const u16* yr = y3g + (size_t)bm*64*CH3 + tid;
  float mx = -1e30f;
  for (int e = 0; e < cnt; ++e) {
    float v = bf2f(yr[e*CH3]);
    mx = fmaxf(mx, fmaxf(fmaf(v, a, b), 0.f));
  }
  out0[(size_t)bm*CH3 + tid] = mx;
}

// ---------------------------------------------------------------- stage 4B (fallback): recompute y3 from y2
__global__ __launch_bounds__(256) void k_s4r(const u16* __restrict__ y2g,
                                             const float* __restrict__ SC,
                                             const float* __restrict__ W3,
                                             const int* __restrict__ cntpc,
                                             float* __restrict__ out0) {
  __shared__ float Hs[64*65];
  __shared__ float ABs[128];
  __shared__ float AB3[256];
  __shared__ int   cntS;
  const int tid = threadIdx.x, bm = blockIdx.x;
  if (tid == 0) cntS = cntpc[bm];
  if (tid < 128) ABs[tid] = SC[128 + tid];
  ((float*)AB3)[tid] = SC[256 + tid];   // A3(128) B3(128)
  __syncthreads();
  {
    const u32* yt = (const u32*)y2g + (size_t)bm*2048;
    #pragma unroll
    for (int rep = 0; rep < 8; ++rep) {
      int g = rep*256 + tid;
      int e = g >> 5, c2 = g & 31, ch = c2*2;
      u32 v = yt[g];
      float lo = fmaxf(fmaf(bf2f((u16)(v & 0xffff)), ABs[ch],   ABs[64+ch]),   0.f);
      float hi = fmaxf(fmaf(bf2f((u16)(v >> 16)),    ABs[ch+1], ABs[64+ch+1]), 0.f);
      Hs[e*65 + ch] = lo; Hs[e*65 + ch + 1] = hi;
    }
  }
  __syncthreads();
  const int edge = tid & 63;
  const int col  = __builtin_amdgcn_readfirstlane(tid >> 6);
  float acc[32];
  #pragma unroll
  for (int j = 0; j < 32; ++j) acc[j] = 0.f;
  const float* hrow = Hs + edge*65;
  const float* wcol = W3 + col*32;
  for (int k = 0; k < CH2; ++k) {
    float hk = hrow[k];
    const float4* w4 = (const float4*)(wcol + k*CH3);
    #pragma unroll
    for (int q = 0; q < 8; ++q) {
      float4 wv = w4[q];
      acc[q*4+0] = fmaf(hk, wv.x, acc[q*4+0]);
      acc[q*4+1] = fmaf(hk, wv.y, acc[q*4+1]);
      acc[q*4+2] = fmaf(hk, wv.z, acc[q*4+2]);
      acc[q*4+3] = fmaf(hk, wv.w, acc[q*4+3]);
    }
  }
  const bool valid = edge < cntS;
  #pragma unroll
  for (int j = 0; j < 32; ++j) {
    int ch = col*32 + j;
    float h = fmaxf(fmaf(acc[j], AB3[ch], AB3[128+ch]), 0.f);
    float mx = wmax(valid ? h : -1e30f);
    if (edge == 0) out0[(size_t)bm*CH3 + ch] = mx;
  }
}

// ---------------------------------------------------------------- finalize
__global__ void k_finalize(const float* __restrict__ Spart,
                           const float* __restrict__ g, const float* __restrict__ bb,
                           const int* __restrict__ cnt_total,
                           float* __restrict__ Aout, float* __restrict__ Bout, int C) {
  int c = threadIdx.x;
  if (c < C) {
    float s = 0.f, q = 0.f;
    for (int sl = 0; sl < NSLOT; ++sl) {
      s += Spart[sl*256 + c];
      q += Spart[sl*256 + 128 + c];
    }
    float n = (float)(*cnt_total); if (n < 1.f) n = 1.f;
    float mu  = s / n;
    float var = q / n - mu*mu; if (var < 0.f) var = 0.f;
    float inv = 1.0f / sqrtf(var + 1e-5f);
    float a = g[c] * inv;
    Aout[c] = a;
    Bout[c] = bb[c] - mu*a;
  }
}

// ---------------------------------------------------------------- host
extern "C" void kernel_launch(void* const* d_in, const int* in_sizes, int n_in,
                              void* d_out, int out_size, void* d_ws, size_t ws_size,
                              hipStream_t stream) {
  (void)in_sizes; (void)n_in; (void)out_size;
  const float* x   = (const float*)d_in[0];
  const float* pos = (const float*)d_in[1];
  const float* W1  = (const float*)d_in[3];
  const float* g1  = (const float*)d_in[4];
  const float* b1  = (const float*)d_in[5];
  const float* W2  = (const float*)d_in[6];
  const float* g2  = (const float*)d_in[7];
  const float* b2  = (const float*)d_in[8];
  const float* W3  = (const float*)d_in[9];
  const float* g3  = (const float*)d_in[10];
  const float* b3  = (const float*)d_in[11];

  float* out0     = (float*)d_out;
  float* out_cent = out0 + (size_t)NB*MC*CH3;
  float* out_bsel = out_cent + (size_t)NB*MC*3;

  char* base = (char*)d_ws;
  size_t off = 0;
  auto carve = [&](size_t bytes) -> char* {
    char* p = base + off;
    off = (off + bytes + 255) & ~(size_t)255;
    return p;
  };
  float* centf = (float*)carve(sizeof(float)*NB*MC*3);
  int*   cntpc = (int*)  carve(sizeof(int)*NB*MC);
  char*  zeroblk = carve(256 + 3*NSLOT*256*sizeof(float));
  int*   cnt_total = (int*)zeroblk;
  int*   taskctr   = cnt_total + 1;
  int*   progress  = cnt_total + 2;    // 8 ints
  float* Sp1 = (float*)(zeroblk + 256);
  float* Sp2 = Sp1 + NSLOT*256;
  float* Sp3 = Sp2 + NSLOT*256;
  float* SC = (float*)carve(512*sizeof(float));  // A1 B1 A2 B2 A3(128) B3(128)
  u16* y1g = (u16*)carve((size_t)NE*CH1*2);
  u16* y2g = (u16*)carve((size_t)NE*CH2*2);
  u16* y3g = (u16*)carve((size_t)NE*CH3*2);
  bool have_y3 = (ws_size >= off);

  hipMemsetAsync(zeroblk, 0, 256 + 3*NSLOT*256*sizeof(float), stream);
  k_front<<<NBLK, 512, DYNLDS, stream>>>(x, pos, centf, out_cent, out_bsel,
                                         W1, Sp1, y1g, cntpc, cnt_total, progress, taskctr);
  k_finalize<<<1, 128, 0, stream>>>(Sp1, g1, b1, cnt_total, SC + 0,   SC + 64,  CH1);
  dim3 sg(NB*MC), sb(256);
  k_s2<<<sg, sb, 0, stream>>>(y1g, SC, W2, cntpc, Sp2, y2g);
  k_finalize<<<1, 128, 0, stream>>>(Sp2, g2, b2, cnt_total, SC + 128, SC + 192, CH2);
  if (have_y3) {
    k_s3<true><<<sg, sb, 0, stream>>>(y2g, SC, W3, cntpc, Sp3, y3g, out0);
    k_finalize<<<1, 128, 0, stream>>>(Sp3, g3, b3, cnt_total, SC + 256, SC + 384, CH3);
    k_s4<<<sg, 128, 0, stream>>>(y3g, SC, cntpc, out0);
  } else {
    k_s3<false><<<sg, sb, 0, stream>>>(y2g, SC, W3, cntpc, Sp3, y3g, out0);
    k_finalize<<<1, 128, 0, stream>>>(Sp3, g3, b3, cnt_total, SC + 256, SC + 384, CH3);
    k_s4r<<<sg, sb, 0, stream>>>(y2g, SC, W3, cntpc, out0);
  }
}

// Round 11
// 1288.266 us; speedup vs baseline: 1.1835x; 1.0688x over previous
//
#include <hip/hip_runtime.h>
#include <stdint.h>

#define NB   8
#define NPTS 4096
#define CINV 64
#define MC   1024
#define KNB  64
#define NE   (NB*MC*KNB)
#define K1   67
#define CH1  64
#define CH2  64
#define CH3  128
#define NSLOT 64
#define CAP  2048
#define NTASK (NB*MC)
#define NBLK 256      // == #CUs

typedef unsigned short u16;
typedef unsigned int   u32;
typedef unsigned long long u64;

static __device__ __forceinline__ float bf2f(u16 b){ return __uint_as_float(((u32)b)<<16); }
static __device__ __forceinline__ u16  f2bf(float f){
  u32 u = __float_as_uint(f);
  return (u16)((u + 0x7fffu + ((u>>16)&1u)) >> 16);
}
// Exact replica of reference distance: square each diff, sum as (x+y)+z, NO fma contraction.
static __device__ __forceinline__ float d2ref(float ax,float ay,float az,
                                              float bx,float by,float bz){
  float dx = ax-bx, dy = ay-by, dz = az-bz;
  return __fadd_rn(__fadd_rn(__fmul_rn(dx,dx), __fmul_rn(dy,dy)), __fmul_rn(dz,dz));
}
static __device__ __forceinline__ float wsum(float v){
  #pragma unroll
  for (int off = 32; off > 0; off >>= 1) v += __shfl_xor(v, off);
  return v;
}
static __device__ __forceinline__ float wmax(float v){
  #pragma unroll
  for (int off = 32; off > 0; off >>= 1) v = fmaxf(v, __shfl_xor(v, off));
  return v;
}
// One DPP max step: v = max(v, dpp_shuffle(v)). Pure VALU (no DS pipe).
template<int CTRL, int RMASK>
static __device__ __forceinline__ float dppmaxstep(float v){
  int t = __builtin_amdgcn_update_dpp(__float_as_int(v), __float_as_int(v),
                                      CTRL, RMASK, 0xF, false);
  return fmaxf(v, __int_as_float(t));
}
// Full wave64 max -> broadcast via readlane(63).
static __device__ __forceinline__ float wavemax_dpp(float v){
  v = dppmaxstep<0xB1, 0xF>(v);
  v = dppmaxstep<0x4E, 0xF>(v);
  v = dppmaxstep<0x141,0xF>(v);
  v = dppmaxstep<0x140,0xF>(v);
  v = dppmaxstep<0x142,0xA>(v);
  v = dppmaxstep<0x143,0xC>(v);
  return __int_as_float(__builtin_amdgcn_readlane(__float_as_int(v), 63));
}

// ---------------------------------------------------------------- fused front kernel
struct FpsL {
  float px[NPTS], py[NPTS], pz[NPTS];
  int   sIdx[MC];
  float2 cand[16];   // (dist, idx-as-float), double-buffered 2x8
  float4 cbuf[16];   // centroid staging: flush 16 rows per tile to global
};
struct WkL {
  u64   keys[CAP];        // ball-query sort keys
  float Hs[64*69];        // stage-1 H tile (odd pitch)
  int   nbrS[64];
  float red[8][16];
  float cxyz[3];
  int   scnt;
  int   task;
};
union FrontL { FpsL f; WkL w; };

__global__ __launch_bounds__(512) void k_front(const float* __restrict__ x,
                                               const float* __restrict__ pos,
                                               float* __restrict__ centf,
                                               float* __restrict__ out_cent,
                                               float* __restrict__ out_bsel,
                                               const float* __restrict__ W1,
                                               float* __restrict__ Spart,
                                               u16* __restrict__ y1g,
                                               int* __restrict__ cntpc,
                                               int* __restrict__ cnt_total,
                                               int* __restrict__ progress,
                                               int* __restrict__ taskctr) {
  __shared__ FrontL L;
  const int tid = threadIdx.x;

  if (blockIdx.x < NB) {
    // ============ FPS producer: 8 waves, vcc-free scan, 1 barrier/iter
    const int b = blockIdx.x;
    for (int i = tid; i < NPTS; i += 512) {
      size_t o = ((size_t)b*NPTS + i)*3;
      L.f.px[i] = pos[o]; L.f.py[i] = pos[o+1]; L.f.pz[i] = pos[o+2];
    }
    __syncthreads();

    float cxr[8], cyr[8], czr[8], dist[8];
    #pragma unroll
    for (int j = 0; j < 8; ++j) {
      int p = tid*8 + j;
      cxr[j] = L.f.px[p]; cyr[j] = L.f.py[p]; czr[j] = L.f.pz[p];
      dist[j] = 1e10f;
    }
    const int lane = tid & 63, w = tid >> 6;
    float qx = L.f.px[0], qy = L.f.py[0], qz = L.f.pz[0];
    if (tid == 0) {
      L.f.sIdx[0] = 0;
      L.f.cbuf[0] = make_float4(qx, qy, qz, 0.f);
    }

    for (int it = 1; it < MC; ++it) {
      // ---- scan: pure min/max, no compares, no vcc
      #pragma unroll
      for (int j = 0; j < 8; ++j) {
        float d = d2ref(cxr[j], cyr[j], czr[j], qx, qy, qz);
        dist[j] = fminf(dist[j], d);
      }
      float m01 = fmaxf(dist[0], dist[1]), m23 = fmaxf(dist[2], dist[3]);
      float m45 = fmaxf(dist[4], dist[5]), m67 = fmaxf(dist[6], dist[7]);
      float lmax = fmaxf(fmaxf(m01, m23), fmaxf(m45, m67));
      // ---- wave max (DPP) + lowest winning lane = lowest index
      float gmax = wavemax_dpp(lmax);
      u64 mm = __ballot(lmax == gmax);
      int wl = __ffsll((unsigned long long)mm) - 1;
      const int base = (it & 1) * 8;
      if (lane == wl) {
        int jj = 7;                       // winner lane: lowest j matching gmax
        #pragma unroll
        for (int j = 6; j >= 0; --j) if (dist[j] == gmax) jj = j;
        L.f.cand[base + w] = make_float2(gmax, (float)(tid*8 + jj));
      }
      __syncthreads();
      // ---- every wave resolves the 8 candidates (no second barrier)
      float2 cq = L.f.cand[base + (lane & 7)];
      float dm = cq.x;
      dm = dppmaxstep<0xB1, 0xF>(dm);
      dm = dppmaxstep<0x4E, 0xF>(dm);
      dm = dppmaxstep<0x141,0xF>(dm);     // max over each 8-group
      u64 m2 = __ballot(cq.x == dm);
      int wc = (__ffsll((unsigned long long)m2) - 1) & 7;  // lowest cand = lowest wave = lowest idx
      int wi = (int)__shfl(cq.y, (lane & ~7) | wc);
      qx = L.f.px[wi]; qy = L.f.py[wi]; qz = L.f.pz[wi];   // broadcast LDS reads
      // flush PREVIOUS 16-row tile then release-publish progress
      if ((it & 15) == 0 && tid < 16) {
        int mrow = it - 16 + tid;
        float4 cc = L.f.cbuf[tid];
        int r = b*MC + mrow;
        centf[r*3+0] = cc.x; centf[r*3+1] = cc.y; centf[r*3+2] = cc.z;
        if (tid == 0)
          __hip_atomic_store(progress + b, it, __ATOMIC_RELEASE, __HIP_MEMORY_SCOPE_AGENT);
      }
      if (tid == 0) {
        L.f.sIdx[it] = wi;
        L.f.cbuf[it & 15] = make_float4(qx, qy, qz, 0.f);
      }
    }
    __syncthreads();
    // final tile flush (rows MC-16..MC-1) + progress = MC
    if (tid < 16) {
      int mrow = MC - 16 + tid;
      float4 cc = L.f.cbuf[tid];
      int r = b*MC + mrow;
      centf[r*3+0] = cc.x; centf[r*3+1] = cc.y; centf[r*3+2] = cc.z;
      if (tid == 0)
        __hip_atomic_store(progress + b, MC, __ATOMIC_RELEASE, __HIP_MEMORY_SCOPE_AGENT);
    }
    // epilogue: out_cent / out_bsel from sIdx (off the critical path)
    for (int m2_ = tid; m2_ < MC; m2_ += 512) {
      int i = L.f.sIdx[m2_];
      int r = b*MC + m2_;
      out_cent[r*3+0] = L.f.px[i]; out_cent[r*3+1] = L.f.py[i]; out_cent[r*3+2] = L.f.pz[i];
      out_bsel[r] = (float)b;
    }
    return;
  }

  // ============ persistent workers: ball query + stage-1 per centroid (512 thr)
  for (;;) {
    if (tid == 0) {
      int t = atomicAdd(taskctr, 1);
      L.w.task = t;
      if (t < NTASK) {
        int m = t >> 3, b = t & 7;
        while (__hip_atomic_load(progress + b, __ATOMIC_ACQUIRE, __HIP_MEMORY_SCOPE_AGENT) < m + 1)
          __builtin_amdgcn_s_sleep(8);
        int bm = b*MC + m;
        L.w.cxyz[0] = __hip_atomic_load(centf + bm*3 + 0, __ATOMIC_RELAXED, __HIP_MEMORY_SCOPE_AGENT);
        L.w.cxyz[1] = __hip_atomic_load(centf + bm*3 + 1, __ATOMIC_RELAXED, __HIP_MEMORY_SCOPE_AGENT);
        L.w.cxyz[2] = __hip_atomic_load(centf + bm*3 + 2, __ATOMIC_RELAXED, __HIP_MEMORY_SCOPE_AGENT);
      }
      L.w.scnt = 0;
    }
    __syncthreads();
    const int t = L.w.task;
    if (t >= NTASK) return;
    const int m = t >> 3, b = t & 7, bm = b*MC + m;
    const float cx = L.w.cxyz[0], cy = L.w.cxyz[1], cz = L.w.cxyz[2];

    // ---- ball query (exact ref semantics)
    for (int i = tid; i < NPTS; i += 512) {
      size_t o = ((size_t)b*NPTS + i)*3;
      float d = d2ref(cx, cy, cz, pos[o], pos[o+1], pos[o+2]);
      if (d <= 0.04f) {
        int p = atomicAdd(&L.w.scnt, 1);
        if (p < CAP) L.w.keys[p] = ((u64)__float_as_uint(d) << 32) | (u32)i;
      }
    }
    __syncthreads();
    int n = L.w.scnt; if (n > CAP) n = CAP;
    int P = 64; while (P < n) P <<= 1;
    for (int i = n + tid; i < P; i += 512) L.w.keys[i] = ~0ull;
    __syncthreads();
    for (int ks = 2; ks <= P; ks <<= 1)
      for (int js = ks >> 1; js > 0; js >>= 1) {
        for (int i = tid; i < P; i += 512) {
          int l = i ^ js;
          if (l > i) {
            u64 a = L.w.keys[i], c = L.w.keys[l];
            bool up = ((i & ks) == 0);
            if ((a > c) == up) { L.w.keys[i] = c; L.w.keys[l] = a; }
          }
        }
        __syncthreads();
      }
    const int c = n < KNB ? n : KNB;
    if (tid < KNB) L.w.nbrS[tid] = (tid < c) ? (int)(u32)(L.w.keys[tid] & 0xffffffffu) : 0;
    if (tid == 0) { cntpc[bm] = c; atomicAdd(cnt_total, c); }
    __syncthreads();

    // ---- stage-1: H = [x_j, p_j - c_i] (64x67) staged in LDS
    {
      const int ge = tid >> 3, qb = tid & 7;
      const float4* xr = (const float4*)(x + ((size_t)(b*NPTS + L.w.nbrS[ge]))*CINV);
      #pragma unroll
      for (int rep = 0; rep < 2; ++rep) {
        int q = qb + rep*8;
        float4 v = xr[q];
        float* d = L.w.Hs + ge*69 + q*4;
        d[0] = v.x; d[1] = v.y; d[2] = v.z; d[3] = v.w;
      }
    }
    if (tid < 64) {
      int row = b*NPTS + L.w.nbrS[tid];
      L.w.Hs[tid*69+64] = pos[(size_t)row*3+0] - cx;
      L.w.Hs[tid*69+65] = pos[(size_t)row*3+1] - cy;
      L.w.Hs[tid*69+66] = pos[(size_t)row*3+2] - cz;
    }
    __syncthreads();

    // ---- GEMM: thread = (edge, col of 8 ch); W via wave-uniform SCALAR loads
    const int edge = tid & 63;
    const int col  = __builtin_amdgcn_readfirstlane(tid >> 6);  // 0..7
    float acc[8];
    #pragma unroll
    for (int j = 0; j < 8; ++j) acc[j] = 0.f;
    const float* hrow = L.w.Hs + edge*69;
    const float* wcol = W1 + col*8;
    for (int k = 0; k < K1; ++k) {
      float hk = hrow[k];
      const float4* w4 = (const float4*)(wcol + k*CH1);
      float4 a = w4[0], bq = w4[1];
      acc[0] = fmaf(hk, a.x,  acc[0]); acc[1] = fmaf(hk, a.y,  acc[1]);
      acc[2] = fmaf(hk, a.z,  acc[2]); acc[3] = fmaf(hk, a.w,  acc[3]);
      acc[4] = fmaf(hk, bq.x, acc[4]); acc[5] = fmaf(hk, bq.y, acc[5]);
      acc[6] = fmaf(hk, bq.z, acc[6]); acc[7] = fmaf(hk, bq.w, acc[7]);
    }
    const bool valid = edge < c;
    #pragma unroll
    for (int j = 0; j < 8; ++j) acc[j] = valid ? acc[j] : 0.f;
    u32* dst = (u32*)(y1g + ((size_t)bm*64 + edge)*CH1 + col*8);
    #pragma unroll
    for (int j = 0; j < 4; ++j)
      dst[j] = (u32)f2bf(acc[2*j]) | ((u32)f2bf(acc[2*j+1]) << 16);
    #pragma unroll
    for (int j = 0; j < 8; ++j) {
      float s = wsum(acc[j]);
      float q = wsum(acc[j]*acc[j]);
      if (edge == 0) { L.w.red[col][j] = s; L.w.red[col][8+j] = q; }
    }
    __syncthreads();
    const int slot = bm & (NSLOT-1);
    if (tid < 64)  atomicAdd(&Spart[slot*256 + tid], L.w.red[tid>>3][tid&7]);
    else if (tid < 128) {
      int cc = tid - 64;
      atomicAdd(&Spart[slot*256 + 128 + cc], L.w.red[cc>>3][8 + (cc&7)]);
    }
    // top-of-loop __syncthreads() isolates this task's LDS reads from next task's writes
  }
}

// ---------------------------------------------------------------- stage 2: relu(bn1(y1)) @ W2
__global__ __launch_bounds__(256) void k_s2(const u16* __restrict__ y1g,
                                            const float* __restrict__ SC,
                                            const float* __restrict__ W2,
                                            const int* __restrict__ cntpc,
                                            float* __restrict__ Spart,
                                            u16* __restrict__ y2g) {
  __shared__ float Hs[64*65];
  __shared__ float ABs[128];
  __shared__ float red[4][32];
  __shared__ int   cntS;
  const int tid = threadIdx.x, bm = blockIdx.x;
  if (tid == 0) cntS = cntpc[bm];
  if (tid < 128) ABs[tid] = SC[tid];            // A1(64) B1(64)
  __syncthreads();
  {
    const u32* yt = (const u32*)y1g + (size_t)bm*2048;  // 64 edges * 32 u32
    #pragma unroll
    for (int rep = 0; rep < 8; ++rep) {
      int g = rep*256 + tid;
      int e = g >> 5, c2 = g & 31, ch = c2*2;
      u32 v = yt[g];
      float lo = fmaxf(fmaf(bf2f((u16)(v & 0xffff)), ABs[ch],   ABs[64+ch]),   0.f);
      float hi = fmaxf(fmaf(bf2f((u16)(v >> 16)),    ABs[ch+1], ABs[64+ch+1]), 0.f);
      Hs[e*65 + ch] = lo; Hs[e*65 + ch + 1] = hi;
    }
  }
  __syncthreads();

  const int edge = tid & 63;
  const int col  = __builtin_amdgcn_readfirstlane(tid >> 6);
  float acc[16];
  #pragma unroll
  for (int j = 0; j < 16; ++j) acc[j] = 0.f;
  const float* hrow = Hs + edge*65;
  const float* wcol = W2 + col*16;
  for (int k = 0; k < CH1; ++k) {
    float hk = hrow[k];
    const float4* w4 = (const float4*)(wcol + k*CH2);
    #pragma unroll
    for (int q = 0; q < 4; ++q) {
      float4 wv = w4[q];
      acc[q*4+0] = fmaf(hk, wv.x, acc[q*4+0]);
      acc[q*4+1] = fmaf(hk, wv.y, acc[q*4+1]);
      acc[q*4+2] = fmaf(hk, wv.z, acc[q*4+2]);
      acc[q*4+3] = fmaf(hk, wv.w, acc[q*4+3]);
    }
  }
  const bool valid = edge < cntS;
  #pragma unroll
  for (int j = 0; j < 16; ++j) acc[j] = valid ? acc[j] : 0.f;
  u32* dst = (u32*)(y2g + ((size_t)bm*64 + edge)*CH2 + col*16);
  #pragma unroll
  for (int j = 0; j < 8; ++j)
    dst[j] = (u32)f2bf(acc[2*j]) | ((u32)f2bf(acc[2*j+1]) << 16);
  #pragma unroll
  for (int j = 0; j < 16; ++j) {
    float s = wsum(acc[j]);
    float q = wsum(acc[j]*acc[j]);
    if (edge == 0) { red[col][j] = s; red[col][16+j] = q; }
  }
  __syncthreads();
  const int slot = bm & (NSLOT-1);
  if (tid < 64)  atomicAdd(&Spart[slot*256 + tid], red[tid>>4][tid&15]);
  else if (tid < 128) {
    int c = tid - 64;
    atomicAdd(&Spart[slot*256 + 128 + c], red[c>>4][16 + (c&15)]);
  }
}

// ---------------------------------------------------------------- stage 3: relu(bn2(y2)) @ W3
template<bool STORE>
__global__ __launch_bounds__(256) void k_s3(const u16* __restrict__ y2g,
                                            const float* __restrict__ SC,
                                            const float* __restrict__ W3,
                                            const int* __restrict__ cntpc,
                                            float* __restrict__ Spart,
                                            u16* __restrict__ y3g,
                                            float* __restrict__ out0) {
  __shared__ float Hs[64*65];
  __shared__ float ABs[128];
  __shared__ float red[4][64];
  __shared__ int   cntS;
  const int tid = threadIdx.x, bm = blockIdx.x;
  if (tid == 0) cntS = cntpc[bm];
  if (tid < 128) ABs[tid] = SC[128 + tid];      // A2(64) B2(64)
  __syncthreads();
  {
    const u32* yt = (const u32*)y2g + (size_t)bm*2048;
    #pragma unroll
    for (int rep = 0; rep < 8; ++rep) {
      int g = rep*256 + tid;
      int e = g >> 5, c2 = g & 31, ch = c2*2;
      u32 v = yt[g];
      float lo = fmaxf(fmaf(bf2f((u16)(v & 0xffff)), ABs[ch],   ABs[64+ch]),   0.f);
      float hi = fmaxf(fmaf(bf2f((u16)(v >> 16)),    ABs[ch+1], ABs[64+ch+1]), 0.f);
      Hs[e*65 + ch] = lo; Hs[e*65 + ch + 1] = hi;
    }
  }
  __syncthreads();

  const int edge = tid & 63;
  const int col  = __builtin_amdgcn_readfirstlane(tid >> 6);  // owns 32 of 128 ch
  float acc[32];
  #pragma unroll
  for (int j = 0; j < 32; ++j) acc[j] = 0.f;
  const float* hrow = Hs + edge*65;
  const float* wcol = W3 + col*32;
  for (int k = 0; k < CH2; ++k) {
    float hk = hrow[k];
    const float4* w4 = (const float4*)(wcol + k*CH3);
    #pragma unroll
    for (int q = 0; q < 8; ++q) {
      float4 wv = w4[q];
      acc[q*4+0] = fmaf(hk, wv.x, acc[q*4+0]);
      acc[q*4+1] = fmaf(hk, wv.y, acc[q*4+1]);
      acc[q*4+2] = fmaf(hk, wv.z, acc[q*4+2]);
      acc[q*4+3] = fmaf(hk, wv.w, acc[q*4+3]);
    }
  }
  const bool valid = edge < cntS;
  #pragma unroll
  for (int j = 0; j < 32; ++j) acc[j] = valid ? acc[j] : 0.f;
  if constexpr (STORE) {
    u32* dst = (u32*)(y3g + ((size_t)bm*64 + edge)*CH3 + col*32);
    #pragma unroll
    for (int j = 0; j < 16; ++j)
      dst[j] = (u32)f2bf(acc[2*j]) | ((u32)f2bf(acc[2*j+1]) << 16);
  }
  #pragma unroll
  for (int j = 0; j < 32; ++j) {
    float s = wsum(acc[j]);
    float q = wsum(acc[j]*acc[j]);
    if (edge == 0) { red[col][j] = s; red[col][32+j] = q; }
  }
  __syncthreads();
  const int slot = bm & (NSLOT-1);
  if (tid < 128) atomicAdd(&Spart[slot*256 + tid], red[tid>>5][tid&31]);
  else {
    int c = tid - 128;
    atomicAdd(&Spart[slot*256 + 128 + c], red[c>>5][32 + (c&31)]);
  }
}

// ---------------------------------------------------------------- stage 4A: bn3+relu+maxpool from stored y3
__global__ __launch_bounds__(128) void k_s4(const u16* __restrict__ y3g,
                                            const float* __restrict__ SC,
                                            const int* __restrict__ cntpc,
                                            float* __restrict__ out0) {
  const int tid = threadIdx.x, bm = blockIdx.x;
  const int cnt = cntpc[bm];
  const float a = SC[256 + tid], b = SC[384 + tid];
  const u16* yr = y3g + (size_t)bm*64*CH3 + tid;
  float mx = -1e30f;
  for (int e = 0; e < cnt; ++e) {
    float v = bf2f(yr[e*CH3]);
    mx = fmaxf(mx, fmaxf(fmaf(v, a, b), 0.f));
  }
  out0[(size_t)bm*CH3 + tid] = mx;
}

// ---------------------------------------------------------------- stage 4B (fallback): recompute y3 from y2
__global__ __launch_bounds__(256) void k_s4r(const u16* __restrict__ y2g,
                                             const float* __restrict__ SC,
                                             const float* __restrict__ W3,
                                             const int* __restrict__ cntpc,
                                             float* __restrict__ out0) {
  __shared__ float Hs[64*65];
  __shared__ float ABs[128];
  __shared__ float AB3[256];
  __shared__ int   cntS;
  const int tid = threadIdx.x, bm = blockIdx.x;
  if (tid == 0) cntS = cntpc[bm];
  if (tid < 128) ABs[tid] = SC[128 + tid];
  ((float*)AB3)[tid] = SC[256 + tid];   // A3(128) B3(128)
  __syncthreads();
  {
    const u32* yt = (const u32*)y2g + (size_t)bm*2048;
    #pragma unroll
    for (int rep = 0; rep < 8; ++rep) {
      int g = rep*256 + tid;
      int e = g >> 5, c2 = g & 31, ch = c2*2;
      u32 v = yt[g];
      float lo = fmaxf(fmaf(bf2f((u16)(v & 0xffff)), ABs[ch],   ABs[64+ch]),   0.f);
      float hi = fmaxf(fmaf(bf2f((u16)(v >> 16)),    ABs[ch+1], ABs[64+ch+1]), 0.f);
      Hs[e*65 + ch] = lo; Hs[e*65 + ch + 1] = hi;
    }
  }
  __syncthreads();
  const int edge = tid & 63;
  const int col  = __builtin_amdgcn_readfirstlane(tid >> 6);
  float acc[32];
  #pragma unroll
  for (int j = 0; j < 32; ++j) acc[j] = 0.f;
  const float* hrow = Hs + edge*65;
  const float* wcol = W3 + col*32;
  for (int k = 0; k < CH2; ++k) {
    float hk = hrow[k];
    const float4* w4 = (const float4*)(wcol + k*CH3);
    #pragma unroll
    for (int q = 0; q < 8; ++q) {
      float4 wv = w4[q];
      acc[q*4+0] = fmaf(hk, wv.x, acc[q*4+0]);
      acc[q*4+1] = fmaf(hk, wv.y, acc[q*4+1]);
      acc[q*4+2] = fmaf(hk, wv.z, acc[q*4+2]);
      acc[q*4+3] = fmaf(hk, wv.w, acc[q*4+3]);
    }
  }
  const bool valid = edge < cntS;
  #pragma unroll
  for (int j = 0; j < 32; ++j) {
    int ch = col*32 + j;
    float h = fmaxf(fmaf(acc[j], AB3[ch], AB3[128+ch]), 0.f);
    float mx = wmax(valid ? h : -1e30f);
    if (edge == 0) out0[(size_t)bm*CH3 + ch] = mx;
  }
}

// ---------------------------------------------------------------- finalize
__global__ void k_finalize(const float* __restrict__ Spart,
                           const float* __restrict__ g, const float* __restrict__ bb,
                           const int* __restrict__ cnt_total,
                           float* __restrict__ Aout, float* __restrict__ Bout, int C) {
  int c = threadIdx.x;
  if (c < C) {
    float s = 0.f, q = 0.f;
    for (int sl = 0; sl < NSLOT; ++sl) {
      s += Spart[sl*256 + c];
      q += Spart[sl*256 + 128 + c];
    }
    float n = (float)(*cnt_total); if (n < 1.f) n = 1.f;
    float mu  = s / n;
    float var = q / n - mu*mu; if (var < 0.f) var = 0.f;
    float inv = 1.0f / sqrtf(var + 1e-5f);
    float a = g[c] * inv;
    Aout[c] = a;
    Bout[c] = bb[c] - mu*a;
  }
}

// ---------------------------------------------------------------- host
extern "C" void kernel_launch(void* const* d_in, const int* in_sizes, int n_in,
                              void* d_out, int out_size, void* d_ws, size_t ws_size,
                              hipStream_t stream) {
  (void)in_sizes; (void)n_in; (void)out_size;
  const float* x   = (const float*)d_in[0];
  const float* pos = (const float*)d_in[1];
  const float* W1  = (const float*)d_in[3];
  const float* g1  = (const float*)d_in[4];
  const float* b1  = (const float*)d_in[5];
  const float* W2  = (const float*)d_in[6];
  const float* g2  = (const float*)d_in[7];
  const float* b2  = (const float*)d_in[8];
  const float* W3  = (const float*)d_in[9];
  const float* g3  = (const float*)d_in[10];
  const float* b3  = (const float*)d_in[11];

  float* out0     = (float*)d_out;
  float* out_cent = out0 + (size_t)NB*MC*CH3;
  float* out_bsel = out_cent + (size_t)NB*MC*3;

  char* base = (char*)d_ws;
  size_t off = 0;
  auto carve = [&](size_t bytes) -> char* {
    char* p = base + off;
    off = (off + bytes + 255) & ~(size_t)255;
    return p;
  };
  float* centf = (float*)carve(sizeof(float)*NB*MC*3);
  int*   cntpc = (int*)  carve(sizeof(int)*NB*MC);
  char*  zeroblk = carve(256 + 3*NSLOT*256*sizeof(float));
  int*   cnt_total = (int*)zeroblk;
  int*   taskctr   = cnt_total + 1;
  int*   progress  = cnt_total + 2;    // 8 ints
  float* Sp1 = (float*)(zeroblk + 256);
  float* Sp2 = Sp1 + NSLOT*256;
  float* Sp3 = Sp2 + NSLOT*256;
  float* SC = (float*)carve(512*sizeof(float));  // A1 B1 A2 B2 A3(128) B3(128)
  u16* y1g = (u16*)carve((size_t)NE*CH1*2);
  u16* y2g = (u16*)carve((size_t)NE*CH2*2);
  u16* y3g = (u16*)carve((size_t)NE*CH3*2);
  bool have_y3 = (ws_size >= off);

  hipMemsetAsync(zeroblk, 0, 256 + 3*NSLOT*256*sizeof(float), stream);
  k_front<<<NBLK, 512, 0, stream>>>(x, pos, centf, out_cent, out_bsel,
                                    W1, Sp1, y1g, cntpc, cnt_total, progress, taskctr);
  k_finalize<<<1, 128, 0, stream>>>(Sp1, g1, b1, cnt_total, SC + 0,   SC + 64,  CH1);
  dim3 sg(NB*MC), sb(256);
  k_s2<<<sg, sb, 0, stream>>>(y1g, SC, W2, cntpc, Sp2, y2g);
  k_finalize<<<1, 128, 0, stream>>>(Sp2, g2, b2, cnt_total, SC + 128, SC + 192, CH2);
  if (have_y3) {
    k_s3<true><<<sg, sb, 0, stream>>>(y2g, SC, W3, cntpc, Sp3, y3g, out0);
    k_finalize<<<1, 128, 0, stream>>>(Sp3, g3, b3, cnt_total, SC + 256, SC + 384, CH3);
    k_s4<<<sg, 128, 0, stream>>>(y3g, SC, cntpc, out0);
  } else {
    k_s3<false><<<sg, sb, 0, stream>>>(y2g, SC, W3, cntpc, Sp3, y3g, out0);
    k_finalize<<<1, 128, 0, stream>>>(Sp3, g3, b3, cnt_total, SC + 256, SC + 384, CH3);
    k_s4r<<<sg, sb, 0, stream>>>(y2g, SC, W3, cntpc, out0);
  }
}